// Round 8
// baseline (209.666 us; speedup 1.0000x reference)
//
#include <hip/hip_runtime.h>
#include <math.h>

#define Bb 8
#define Cc 128
#define Nn 3136                  // 56*56 real spatial
#define Np 3200                  // padded spatial (50 x 64)
#define Mm (Bb*Cc*Nn)            // elements per output tensor
#define PADX 136                 // xt row stride (u16): 128 data + 8 pad = 272 B (17x16B)
#define PADV 72                  // s_xc / s_pt row stride (u16): 144 B (9x16B)
#define SHIFT2 63.4785818f       // 44 * log2(e): shift in exp2 space
#define SSCALE 1.2011224087f     // sqrt(log2 e): xt pre-scale so energy = e*log2(e)

#define EXP2F(v) __builtin_amdgcn_exp2f(v)   // v_exp_f32; __exp2f collides with glibc macro

typedef unsigned short u16;
typedef unsigned int   u32;
typedef __attribute__((ext_vector_type(8)))  u16      u16x8;
typedef __attribute__((ext_vector_type(8)))  _Float16 f16x8;
typedef __attribute__((ext_vector_type(4)))  _Float16 f16x4;
typedef __attribute__((ext_vector_type(4)))  float    f32x4;
typedef __attribute__((ext_vector_type(16))) float    f32x16;

// ---------------------------------------------------------------------------
// Prep: x f32 -> xt [b][n(3200)][PADX] fp16 * SSCALE (spatial-major) and
// xc [b][c][3200] fp16 unscaled (channel-major); zero-pads rows 3136..3199;
// row_d pads = 1.0. Fused: out slot2 = x copy, slot3 = gamma. grid 400.
// ---------------------------------------------------------------------------
__global__ __launch_bounds__(256) void prep_kernel(const float* __restrict__ x,
                                                   const float* __restrict__ gamma_p,
                                                   float* __restrict__ out,
                                                   u16* __restrict__ xt,
                                                   u16* __restrict__ xc,
                                                   float* __restrict__ row_d) {
    const int bx = blockIdx.x;
    const int b = bx / 50, nblk = bx % 50;
    const int t = threadIdx.x;

    if (nblk == 49) {            // tail: zero-pad spatial rows 3136..3199
        const u16x8 z8 = {0, 0, 0, 0, 0, 0, 0, 0};
        #pragma unroll
        for (int it = 0; it < 4; ++it) {
            const int idx = it * 256 + t, row = idx / 17, seg = idx % 17;
            *(u16x8*)&xt[(size_t)(b * Np + Nn + row) * PADX + seg * 8] = z8;
        }
        if (t < 64) {
            const int idx = 1024 + t, row = idx / 17, seg = idx % 17;
            *(u16x8*)&xt[(size_t)(b * Np + Nn + row) * PADX + seg * 8] = z8;
        }
        #pragma unroll
        for (int it = 0; it < 4; ++it) {
            const int idx = it * 256 + t, c = idx >> 3, seg = idx & 7;
            *(u16x8*)&xc[(size_t)(b * Cc + c) * Np + Nn + seg * 8] = z8;
        }
        if (t < 64) row_d[b * Np + Nn + t] = 1.0f;   // pad denominators: 1/1
        return;
    }

    __shared__ float lx[Cc][65];
    const int n0 = nblk * 64;

    // phase 1: coalesced read + slot-2 copy
    #pragma unroll 8
    for (int r = 0; r < 32; ++r) {
        const int c = r * 4 + (t >> 6);
        const int g = (b * Cc + c) * Nn + n0 + (t & 63);
        const float v = x[g];
        lx[c][t & 63] = v;
        out[(size_t)2 * Mm + g] = v;
    }
    __syncthreads();

    // phase 2: xt rows (n-major, c contiguous), scaled by SSCALE
    {
        const int nl = t & 63, cseg = t >> 6;
        u16x8 hv[4];
        #pragma unroll
        for (int cc = 0; cc < 32; ++cc) {
            const _Float16 hh = (_Float16)(lx[cseg * 32 + cc][nl] * SSCALE);
            hv[cc >> 3][cc & 7] = __builtin_bit_cast(u16, hh);
        }
        const size_t base = (size_t)(b * Np + n0 + nl) * PADX + cseg * 32;
        #pragma unroll
        for (int k = 0; k < 4; ++k) *(u16x8*)&xt[base + k * 8] = hv[k];
    }
    // phase 2b: xc rows (c-major, n contiguous), unscaled
    {
        const int c = t >> 1, half = t & 1;
        u16x8 hv[4];
        #pragma unroll
        for (int k = 0; k < 32; ++k) {
            const _Float16 hh = (_Float16)lx[c][half * 32 + k];
            hv[k >> 3][k & 7] = __builtin_bit_cast(u16, hh);
        }
        const size_t base = (size_t)(b * Cc + c) * Np + n0 + half * 32;
        #pragma unroll
        for (int k = 0; k < 4; ++k) *(u16x8*)&xc[base + k * 8] = hv[k];
    }
    if (bx == 0 && t == 0) out[(size_t)3 * Mm] = gamma_p[0];
}

// ---------------------------------------------------------------------------
// Stats: row_d[b,i] += sum_j exp2(e2_ij - SHIFT2), e2 = scaled masked energy.
// D[m=j][n=i]: A = staged j-rows, B = resident i-rows. grid 784 =
// 8 b * 49 i-blocks * 2 j-halves (25 tiles each over padded 3200).
// ---------------------------------------------------------------------------
__global__ __launch_bounds__(256, 3) void stats_kernel(const u16* __restrict__ xt,
                                                       float* __restrict__ row_d) {
    __shared__ u16 s_jt[64 * PADX];   // 17408 B

    const int bx = blockIdx.x;
    const int b = bx / 98, rem = bx % 98;
    const int i0 = (rem >> 1) * 64, jh = rem & 1;
    const int t = threadIdx.x;
    const int w = t >> 6, l = t & 63, lane = l & 31, h = l >> 5;
    const int igrp = w & 1, jsub = w >> 1;

    f16x8 Bf[8];
    {
        const size_t rb = (size_t)(b * Np + i0 + igrp * 32 + lane) * PADX + h * 8;
        #pragma unroll
        for (int kk = 0; kk < 8; ++kk)
            Bf[kk] = *(const f16x8*)&xt[rb + kk * 16];
    }

    float sa = 0.0f, sb = 0.0f;
    const int jt0 = jh * 25;

    for (int jt = jt0; jt < jt0 + 25; ++jt) {
        const int j0 = jt * 64;
        __syncthreads();
        {   // contiguous copy: 64 rows x 17 segs
            const u16* src = xt + (size_t)(b * Np + j0) * PADX;
            u16x8 tv[4], tv4;
            #pragma unroll
            for (int it = 0; it < 4; ++it)
                tv[it] = *(const u16x8*)&src[(it * 256 + t) * 8];
            if (t < 64) tv4 = *(const u16x8*)&src[(1024 + t) * 8];
            #pragma unroll
            for (int it = 0; it < 4; ++it)
                *(u16x8*)&s_jt[(it * 256 + t) * 8] = tv[it];
            if (t < 64) *(u16x8*)&s_jt[(1024 + t) * 8] = tv4;
        }
        __syncthreads();

        f32x16 ea, eb;
        #pragma unroll
        for (int r = 0; r < 16; ++r) { ea[r] = 0.0f; eb[r] = 0.0f; }
        const int arow = (jsub * 32 + lane) * PADX + h * 8;
        #pragma unroll
        for (int kk = 0; kk < 4; ++kk) {
            const f16x8 A0 = *(const f16x8*)&s_jt[arow + (2 * kk) * 16];
            const f16x8 A1 = *(const f16x8*)&s_jt[arow + (2 * kk + 1) * 16];
            ea = __builtin_amdgcn_mfma_f32_32x32x16_f16(A0, Bf[2 * kk], ea, 0, 0, 0);
            eb = __builtin_amdgcn_mfma_f32_32x32x16_f16(A1, Bf[2 * kk + 1], eb, 0, 0, 0);
        }

        const bool diag = (j0 == i0) && (jsub == igrp);
        #pragma unroll
        for (int r = 0; r < 16; ++r) {
            const int mrow = (r & 3) + 8 * (r >> 2) + 4 * h;
            float v = ea[r] + eb[r];
            if (diag && (mrow == lane)) v = 0.0f;
            if (r & 1) sb += EXP2F(v - SHIFT2); else sa += EXP2F(v - SHIFT2);
        }
    }

    float ssum = sa + sb;
    ssum += __shfl_xor(ssum, 32, 64);   // combine h-halves (disjoint j-rows)
    if (h == 0) atomicAdd(&row_d[b * Np + i0 + igrp * 32 + lane], ssum);
}

// ---------------------------------------------------------------------------
// Out (partial): for i-half 'half' (1600 rows), accumulate
// p[c][j] = sum_i V[c][i]*exp2(e2_ij-SHIFT2)/d_i, store RAW partials into
// out slot 'half' (scratch; finished by reduce_kernel).
// 256 threads (4 waves), grid 784 = (b, 64-j, half). i-tile 64, 25 iters.
// LDS 45056 B + grid 784 -> 3 blocks/CU truly co-resident.
// ---------------------------------------------------------------------------
__global__ __launch_bounds__(256, 3) void out_kernel(const u16* __restrict__ xt,
                                                     const u16* __restrict__ xc,
                                                     const float* __restrict__ row_d,
                                                     float* __restrict__ out) {
    __shared__ u16 s_xt[64 * PADX];    // 17408 B  i-tile, [i][c]
    __shared__ u16 s_xc[Cc * PADV];    // 18432 B  V tile, [c][i]
    __shared__ u16 s_pt[64 * PADV];    //  9216 B  P^T,    [j][i]

    const int bx = blockIdx.x;
    const int b = bx / 98, rem = bx % 98;
    const int j0 = (rem >> 1) * 64, half = rem & 1;
    const int t = threadIdx.x;
    const int w = t >> 6, l = t & 63, lane = l & 31, h = l >> 5;
    const int isub = w & 1, jgrp = w >> 1;   // energy roles
    const int jg = w & 1,  cp = w >> 1;      // PV roles
    const u16* __restrict__ xtb = xt + (size_t)b * Np * PADX;
    const u16* __restrict__ xcb = xc + (size_t)b * Cc * Np;

    // resident B-frags: j-rows j0 + jgrp*32 + lane
    f16x8 Bj[8];
    {
        const size_t rb = (size_t)(j0 + jgrp * 32 + lane) * PADX + h * 8;
        #pragma unroll
        for (int kk = 0; kk < 8; ++kk)
            Bj[kk] = *(const f16x8*)&xtb[rb + kk * 16];
    }

    f32x16 oa, ob;
    #pragma unroll
    for (int r = 0; r < 16; ++r) { oa[r] = 0.0f; ob[r] = 0.0f; }

    for (int ti = 0; ti < 25; ++ti) {
        const int i0g = (half * 25 + ti) * 64;
        __syncthreads();                     // prior-iter s_xt/s_xc/s_pt reads done
        // stage: s_xt = contiguous 1088 segs; s_xc = 128 c-rows x 8 segs
        {
            const u16* srct = xtb + (size_t)i0g * PADX;
            u16x8 vt[4], vt4, vcr[4];
            #pragma unroll
            for (int it = 0; it < 4; ++it) {
                vt[it] = *(const u16x8*)&srct[(it * 256 + t) * 8];
                const int q = it * 256 + t;
                vcr[it] = *(const u16x8*)&xcb[(size_t)(q >> 3) * Np + i0g + (q & 7) * 8];
            }
            if (t < 64) vt4 = *(const u16x8*)&srct[(1024 + t) * 8];
            #pragma unroll
            for (int it = 0; it < 4; ++it) {
                *(u16x8*)&s_xt[(it * 256 + t) * 8] = vt[it];
                const int q = it * 256 + t;
                *(u16x8*)&s_xc[(q >> 3) * PADV + (q & 7) * 8] = vcr[it];
            }
            if (t < 64) *(u16x8*)&s_xt[(1024 + t) * 8] = vt4;
        }
        __syncthreads();                     // tiles staged

        // energy: D[m=i][n=j], one 32x32 tile per wave, dual K-chains
        f32x16 ea, eb;
        #pragma unroll
        for (int r = 0; r < 16; ++r) { ea[r] = 0.0f; eb[r] = 0.0f; }
        const int arow = (isub * 32 + lane) * PADX + h * 8;
        #pragma unroll
        for (int kk = 0; kk < 4; ++kk) {
            const f16x8 A0 = *(const f16x8*)&s_xt[arow + (2 * kk) * 16];
            const f16x8 A1 = *(const f16x8*)&s_xt[arow + (2 * kk + 1) * 16];
            ea = __builtin_amdgcn_mfma_f32_32x32x16_f16(A0, Bj[2 * kk], ea, 0, 0, 0);
            eb = __builtin_amdgcn_mfma_f32_32x32x16_f16(A1, Bj[2 * kk + 1], eb, 0, 0, 0);
        }

        // P = exp2(masked e2 - SHIFT2)/d -> s_pt[j][i], 4x b64 per wave
        const bool mayDiag = (j0 < i0g + 64) && (i0g < j0 + 64);
        const int ptbase = (jgrp * 32 + lane) * PADV + isub * 32;
        #pragma unroll
        for (int q = 0; q < 4; ++q) {
            const f32x4 dq = *(const f32x4*)&row_d[b * Np + i0g + isub * 32 + q * 8 + h * 4];
            f16x4 pv;
            #pragma unroll
            for (int r = 0; r < 4; ++r) {
                const int m = q * 8 + h * 4 + r;
                float v = ea[q * 4 + r] + eb[q * 4 + r];
                if (mayDiag && (i0g + isub * 32 + m == j0 + jgrp * 32 + lane)) v = 0.0f;
                pv[r] = (_Float16)(EXP2F(v - SHIFT2) * __builtin_amdgcn_rcpf(dq[r]));
            }
            *(f16x4*)&s_pt[ptbase + q * 8 + h * 4] = pv;
        }
        __syncthreads();                     // s_pt complete (cross-wave reads next)

        // PV: D[m=c][n=j], K=64; wave (cp, jg): c-tiles cp*64 and cp*64+32
        const int pbrow = (jg * 32 + lane) * PADV + h * 8;
        const int va0 = (cp * 64 + lane) * PADV + h * 8;
        const int va1 = va0 + 32 * PADV;
        #pragma unroll
        for (int kk = 0; kk < 4; ++kk) {
            const f16x8 Bp  = *(const f16x8*)&s_pt[pbrow + kk * 16];
            const f16x8 Av0 = *(const f16x8*)&s_xc[va0 + kk * 16];
            const f16x8 Av1 = *(const f16x8*)&s_xc[va1 + kk * 16];
            oa = __builtin_amdgcn_mfma_f32_32x32x16_f16(Av0, Bp, oa, 0, 0, 0);
            ob = __builtin_amdgcn_mfma_f32_32x32x16_f16(Av1, Bp, ob, 0, 0, 0);
        }
    }

    // epilogue: store RAW partials to out slot 'half' (no relu/gamma yet)
    float* __restrict__ slotp = out + (size_t)half * Mm;
    #pragma unroll
    for (int r = 0; r < 16; ++r) {
        const int mrow = (r & 3) + 8 * (r >> 2) + 4 * h;
        const int jj = j0 + jg * 32 + lane;
        slotp[(size_t)(b * Cc + cp * 64 + mrow) * Nn + jj] = oa[r];
        slotp[(size_t)(b * Cc + cp * 64 + 32 + mrow) * Nn + jj] = ob[r];
    }
}

// ---------------------------------------------------------------------------
// Reduce: o = relu(p0 + p1); y = gamma*o + x; slot0 = y, slot1 = o (in place).
// grid 784 x 256 thr, 16 floats/thread = Mm exactly.
// ---------------------------------------------------------------------------
__global__ __launch_bounds__(256) void reduce_kernel(const float* __restrict__ x,
                                                     const float* __restrict__ gamma_p,
                                                     float* __restrict__ out) {
    const float gamma = gamma_p[0];
    float* __restrict__ s0 = out;
    float* __restrict__ s1 = out + (size_t)Mm;
    const size_t base = (size_t)blockIdx.x * 4096 + threadIdx.x * 4;
    #pragma unroll
    for (int it = 0; it < 4; ++it) {
        const size_t k = base + it * 1024;
        const f32x4 p0 = *(const f32x4*)&s0[k];
        const f32x4 p1 = *(const f32x4*)&s1[k];
        const f32x4 xv = *(const f32x4*)&x[k];
        f32x4 o, y;
        #pragma unroll
        for (int r = 0; r < 4; ++r) {
            o[r] = fmaxf(p0[r] + p1[r], 0.0f);
            y[r] = fmaf(gamma, o[r], xv[r]);
        }
        *(f32x4*)&s0[k] = y;
        *(f32x4*)&s1[k] = o;
    }
}

extern "C" void kernel_launch(void* const* d_in, const int* in_sizes, int n_in,
                              void* d_out, int out_size, void* d_ws, size_t ws_size,
                              hipStream_t stream) {
    const float* x       = (const float*)d_in[0];
    const float* gamma_p = (const float*)d_in[1];
    float* out = (float*)d_out;

    // ws layout (~13.7 MB): row_d (8x3200 f32) | xt | xc
    float* row_d = (float*)d_ws;
    u16* xt = (u16*)((char*)d_ws + (1 << 17));
    u16* xc = xt + (size_t)Bb * Np * PADX;

    (void)hipMemsetAsync(row_d, 0, (size_t)Bb * Np * sizeof(float), stream);
    prep_kernel  <<<400, 256, 0, stream>>>(x, gamma_p, out, xt, xc, row_d);
    stats_kernel <<<784, 256, 0, stream>>>(xt, row_d);
    out_kernel   <<<784, 256, 0, stream>>>(xt, xc, row_d, out);
    reduce_kernel<<<784, 256, 0, stream>>>(x, gamma_p, out);
}

// Round 10
// 208.765 us; speedup vs baseline: 1.0043x; 1.0043x over previous
//
#include <hip/hip_runtime.h>
#include <math.h>

#define Bb 8
#define Cc 128
#define Nn 3136                  // 56*56 real spatial
#define Np 3200                  // padded spatial (50 x 64)
#define Mm (Bb*Cc*Nn)            // elements per output tensor
#define PADX 136                 // xt row stride (u16): 272 B = 17 x 16B
#define PADV 72                  // xcp / s_pt row stride (u16): 144 B = 9 x 16B
#define SHIFT2 63.4785818f       // 44 * log2(e)
#define SSCALE 1.2011224087f     // sqrt(log2 e): xt pre-scale so energy = e*log2(e)

#define EXP2F(v) __builtin_amdgcn_exp2f(v)

typedef unsigned short u16;
typedef unsigned int   u32;
typedef __attribute__((ext_vector_type(8)))  u16      u16x8;
typedef __attribute__((ext_vector_type(8)))  _Float16 f16x8;
typedef __attribute__((ext_vector_type(4)))  _Float16 f16x4;
typedef __attribute__((ext_vector_type(4)))  float    f32x4;
typedef __attribute__((ext_vector_type(16))) float    f32x16;

// async global->LDS DMA, 16B/lane; HW dest = wave-uniform base + lane*16
__device__ __forceinline__ void dma16(const u16* g, u16* l) {
    __builtin_amdgcn_global_load_lds(
        (const __attribute__((address_space(1))) u32*)(const void*)g,
        (__attribute__((address_space(3))) u32*)(void*)l, 16, 0, 0);
}

// ---------------------------------------------------------------------------
// Prep: x f32 -> xt [b][n(3200)][PADX] fp16 * SSCALE (spatial-major) and
// xcp [b][tile(50)][c(128)][72] fp16 (pre-tiled V, contiguous 18432B tiles
// for DMA staging); zero-pads spatial 3136..3199; row_d pads = 1.0 (real
// rows zeroed by memsetAsync in launcher). Fused: out slot2 = x, slot3 = g.
// ---------------------------------------------------------------------------
__global__ __launch_bounds__(256) void prep_kernel(const float* __restrict__ x,
                                                   const float* __restrict__ gamma_p,
                                                   float* __restrict__ out,
                                                   u16* __restrict__ xt,
                                                   u16* __restrict__ xcp,
                                                   float* __restrict__ row_d) {
    const int bx = blockIdx.x;
    const int b = bx / 50, nblk = bx % 50;
    const int t = threadIdx.x;

    if (nblk == 49) {            // tail: zero-pad spatial rows 3136..3199
        const u16x8 z8 = {0, 0, 0, 0, 0, 0, 0, 0};
        #pragma unroll
        for (int it = 0; it < 4; ++it) {
            const int idx = it * 256 + t, row = idx / 17, seg = idx % 17;
            *(u16x8*)&xt[(size_t)(b * Np + Nn + row) * PADX + seg * 8] = z8;
        }
        if (t < 64) {
            const int idx = 1024 + t, row = idx / 17, seg = idx % 17;
            *(u16x8*)&xt[(size_t)(b * Np + Nn + row) * PADX + seg * 8] = z8;
        }
        u16* tile49 = xcp + (size_t)(b * 50 + 49) * Cc * PADV;
        #pragma unroll
        for (int it = 0; it < 4; ++it)
            *(u16x8*)&tile49[(it * 256 + t) * 8] = z8;
        if (t < 128)
            *(u16x8*)&tile49[(1024 + t) * 8] = z8;
        if (t < 64) row_d[b * Np + Nn + t] = 1.0f;   // pad denominators
        return;
    }

    __shared__ float lx[Cc][65];
    const int n0 = nblk * 64;

    // phase 1: coalesced read + slot-2 copy
    #pragma unroll 8
    for (int r = 0; r < 32; ++r) {
        const int c = r * 4 + (t >> 6);
        const int g = (b * Cc + c) * Nn + n0 + (t & 63);
        const float v = x[g];
        lx[c][t & 63] = v;
        out[(size_t)2 * Mm + g] = v;
    }
    __syncthreads();

    // phase 2: xt rows (n-major, c contiguous), scaled by SSCALE
    {
        const int nl = t & 63, cseg = t >> 6;
        u16x8 hv[4];
        #pragma unroll
        for (int cc = 0; cc < 32; ++cc) {
            const _Float16 hh = (_Float16)(lx[cseg * 32 + cc][nl] * SSCALE);
            hv[cc >> 3][cc & 7] = __builtin_bit_cast(u16, hh);
        }
        const size_t base = (size_t)(b * Np + n0 + nl) * PADX + cseg * 32;
        #pragma unroll
        for (int k = 0; k < 4; ++k) *(u16x8*)&xt[base + k * 8] = hv[k];
    }
    // phase 2b: xcp tile rows (c-major, i contiguous + pad), unscaled
    {
        const int c = t >> 1, half = t & 1;
        u16x8 hv[4];
        #pragma unroll
        for (int k = 0; k < 32; ++k) {
            const _Float16 hh = (_Float16)lx[c][half * 32 + k];
            hv[k >> 3][k & 7] = __builtin_bit_cast(u16, hh);
        }
        const size_t base = ((size_t)(b * 50 + nblk) * Cc + c) * PADV + half * 32;
        #pragma unroll
        for (int k = 0; k < 4; ++k) *(u16x8*)&xcp[base + k * 8] = hv[k];
    }
    if (bx == 0 && t == 0) out[(size_t)3 * Mm] = gamma_p[0];
}

// ---------------------------------------------------------------------------
// Stats: row_d[b,i] += sum_j exp2(e2_ij - SHIFT2). Single-buffered DMA
// staging (m97-verified pattern: sync / DMA issue / sync-drain / compute).
// grid 784 = 8 b * 49 i-blocks * 2 j-halves (25 tiles each over padded 3200).
// ---------------------------------------------------------------------------
__global__ __launch_bounds__(256, 3) void stats_kernel(const u16* __restrict__ xt,
                                                       float* __restrict__ row_d) {
    __shared__ u16 s_jt[64 * PADX];   // 17408 B

    const int bx = blockIdx.x;
    const int b = bx / 98, rem = bx % 98;
    const int i0 = (rem >> 1) * 64, jh = rem & 1;
    const int t = threadIdx.x;
    const int w = t >> 6, l = t & 63, lane = l & 31, h = l >> 5;
    const int igrp = w & 1, jsub = w >> 1;
    const int wb = t & ~63;              // wave-uniform lane base

    f16x8 Bf[8];
    {
        const size_t rb = (size_t)(b * Np + i0 + igrp * 32 + lane) * PADX + h * 8;
        #pragma unroll
        for (int kk = 0; kk < 8; ++kk)
            Bf[kk] = *(const f16x8*)&xt[rb + kk * 16];
    }

    float sa = 0.0f, sb = 0.0f;
    const int jt0 = jh * 25;

    for (int jt = jt0; jt < jt0 + 25; ++jt) {
        const int j0 = jt * 64;
        __syncthreads();                 // all reads of s_jt from prev iter done
        {
            const u16* src = xt + (size_t)(b * Np + j0) * PADX;
            #pragma unroll
            for (int it = 0; it < 4; ++it)
                dma16(&src[(it * 256 + t) * 8], &s_jt[(it * 256 + wb) * 8]);
            if (t < 64) dma16(&src[(1024 + t) * 8], &s_jt[(1024 + wb) * 8]);
        }
        __syncthreads();                 // vmcnt drained -> tile ready

        f32x16 ea, eb;
        #pragma unroll
        for (int r = 0; r < 16; ++r) { ea[r] = 0.0f; eb[r] = 0.0f; }
        const int arow = (jsub * 32 + lane) * PADX + h * 8;
        #pragma unroll
        for (int kk = 0; kk < 4; ++kk) {
            const f16x8 A0 = *(const f16x8*)&s_jt[arow + (2 * kk) * 16];
            const f16x8 A1 = *(const f16x8*)&s_jt[arow + (2 * kk + 1) * 16];
            ea = __builtin_amdgcn_mfma_f32_32x32x16_f16(A0, Bf[2 * kk], ea, 0, 0, 0);
            eb = __builtin_amdgcn_mfma_f32_32x32x16_f16(A1, Bf[2 * kk + 1], eb, 0, 0, 0);
        }

        const bool diag = (j0 == i0) && (jsub == igrp);
        #pragma unroll
        for (int r = 0; r < 16; ++r) {
            const int mrow = (r & 3) + 8 * (r >> 2) + 4 * h;
            float v = ea[r] + eb[r];
            if (diag && (mrow == lane)) v = 0.0f;
            if (r & 1) sb += EXP2F(v - SHIFT2); else sa += EXP2F(v - SHIFT2);
        }
    }

    float ssum = sa + sb;
    ssum += __shfl_xor(ssum, 32, 64);    // combine h-halves (disjoint j-rows)
    if (h == 0) atomicAdd(&row_d[b * Np + i0 + igrp * 32 + lane], ssum);
}

// ---------------------------------------------------------------------------
// Out (partial): p[c][j] = sum_{i in half} V[c][i]*exp2(e2-SHIFT2)/d_i, raw
// partials into out slot 'half'. Single-buffered DMA staging (m97 pattern).
// LDS 45056 B, grid 784 -> 3 blocks/CU co-resident.
// ---------------------------------------------------------------------------
__global__ __launch_bounds__(256, 3) void out_kernel(const u16* __restrict__ xt,
                                                     const u16* __restrict__ xcp,
                                                     const float* __restrict__ row_d,
                                                     float* __restrict__ out) {
    __shared__ u16 s_xt[64 * PADX];    // 17408 B  i-tile [i][c]
    __shared__ u16 s_xc[Cc * PADV];    // 18432 B  V tile [c][i]
    __shared__ u16 s_pt[64 * PADV];    //  9216 B  P^T   [j][i]

    const int bx = blockIdx.x;
    const int b = bx / 98, rem = bx % 98;
    const int j0 = (rem >> 1) * 64, half = rem & 1;
    const int t = threadIdx.x;
    const int w = t >> 6, l = t & 63, lane = l & 31, h = l >> 5;
    const int isub = w & 1, jgrp = w >> 1;   // energy roles
    const int jg = w & 1,  cp = w >> 1;      // PV roles
    const int wb = t & ~63;
    const u16* __restrict__ xtb = xt + (size_t)b * Np * PADX;

    // resident B-frags: j-rows j0 + jgrp*32 + lane
    f16x8 Bj[8];
    {
        const size_t rb = (size_t)(j0 + jgrp * 32 + lane) * PADX + h * 8;
        #pragma unroll
        for (int kk = 0; kk < 8; ++kk)
            Bj[kk] = *(const f16x8*)&xtb[rb + kk * 16];
    }

    f32x16 oa, ob;
    #pragma unroll
    for (int r = 0; r < 16; ++r) { oa[r] = 0.0f; ob[r] = 0.0f; }

    for (int ti = 0; ti < 25; ++ti) {
        const int tile = half * 25 + ti;
        const int i0g = tile * 64;
        __syncthreads();                 // all reads of s_xt/s_xc/s_pt done
        {
            const u16* srct = xtb + (size_t)i0g * PADX;
            const u16* srcc = xcp + (size_t)(b * 50 + tile) * Cc * PADV;
            #pragma unroll
            for (int it = 0; it < 4; ++it) {
                dma16(&srct[(it * 256 + t) * 8], &s_xt[(it * 256 + wb) * 8]);
                dma16(&srcc[(it * 256 + t) * 8], &s_xc[(it * 256 + wb) * 8]);
            }
            if (t < 64)  dma16(&srct[(1024 + t) * 8], &s_xt[(1024 + wb) * 8]);
            if (t < 128) dma16(&srcc[(1024 + t) * 8], &s_xc[(1024 + wb) * 8]);
        }
        __syncthreads();                 // vmcnt drained -> tiles ready

        // energy: D[m=i][n=j], one 32x32 tile per wave, dual K-chains
        f32x16 ea, eb;
        #pragma unroll
        for (int r = 0; r < 16; ++r) { ea[r] = 0.0f; eb[r] = 0.0f; }
        const int arow = (isub * 32 + lane) * PADX + h * 8;
        #pragma unroll
        for (int kk = 0; kk < 4; ++kk) {
            const f16x8 A0 = *(const f16x8*)&s_xt[arow + (2 * kk) * 16];
            const f16x8 A1 = *(const f16x8*)&s_xt[arow + (2 * kk + 1) * 16];
            ea = __builtin_amdgcn_mfma_f32_32x32x16_f16(A0, Bj[2 * kk], ea, 0, 0, 0);
            eb = __builtin_amdgcn_mfma_f32_32x32x16_f16(A1, Bj[2 * kk + 1], eb, 0, 0, 0);
        }

        // P = exp2(masked e2 - SHIFT2)/d -> s_pt[j][i], 4x b64 per wave
        const bool mayDiag = (j0 < i0g + 64) && (i0g < j0 + 64);
        const int ptbase = (jgrp * 32 + lane) * PADV + isub * 32;
        #pragma unroll
        for (int q = 0; q < 4; ++q) {
            const f32x4 dq = *(const f32x4*)&row_d[b * Np + i0g + isub * 32 + q * 8 + h * 4];
            f16x4 pv;
            #pragma unroll
            for (int r = 0; r < 4; ++r) {
                const int m = q * 8 + h * 4 + r;
                float v = ea[q * 4 + r] + eb[q * 4 + r];
                if (mayDiag && (i0g + isub * 32 + m == j0 + jgrp * 32 + lane)) v = 0.0f;
                pv[r] = (_Float16)(EXP2F(v - SHIFT2) * __builtin_amdgcn_rcpf(dq[r]));
            }
            *(f16x4*)&s_pt[ptbase + q * 8 + h * 4] = pv;
        }
        __syncthreads();                 // s_pt complete (cross-wave reads next)

        // PV: D[m=c][n=j], K=64; wave (cp, jg): c-tiles cp*64 and cp*64+32
        const int pbrow = (jg * 32 + lane) * PADV + h * 8;
        const int va0 = (cp * 64 + lane) * PADV + h * 8;
        const int va1 = va0 + 32 * PADV;
        #pragma unroll
        for (int kk = 0; kk < 4; ++kk) {
            const f16x8 Bp  = *(const f16x8*)&s_pt[pbrow + kk * 16];
            const f16x8 Av0 = *(const f16x8*)&s_xc[va0 + kk * 16];
            const f16x8 Av1 = *(const f16x8*)&s_xc[va1 + kk * 16];
            oa = __builtin_amdgcn_mfma_f32_32x32x16_f16(Av0, Bp, oa, 0, 0, 0);
            ob = __builtin_amdgcn_mfma_f32_32x32x16_f16(Av1, Bp, ob, 0, 0, 0);
        }
    }

    // epilogue: store RAW partials to out slot 'half'
    float* __restrict__ slotp = out + (size_t)half * Mm;
    #pragma unroll
    for (int r = 0; r < 16; ++r) {
        const int mrow = (r & 3) + 8 * (r >> 2) + 4 * h;
        const int jj = j0 + jg * 32 + lane;
        slotp[(size_t)(b * Cc + cp * 64 + mrow) * Nn + jj] = oa[r];
        slotp[(size_t)(b * Cc + cp * 64 + 32 + mrow) * Nn + jj] = ob[r];
    }
}

// ---------------------------------------------------------------------------
// Reduce: o = relu(p0 + p1); y = gamma*o + x; slot0 = y, slot1 = o (in place).
// ---------------------------------------------------------------------------
__global__ __launch_bounds__(256) void reduce_kernel(const float* __restrict__ x,
                                                     const float* __restrict__ gamma_p,
                                                     float* __restrict__ out) {
    const float gamma = gamma_p[0];
    float* __restrict__ s0 = out;
    float* __restrict__ s1 = out + (size_t)Mm;
    const size_t base = (size_t)blockIdx.x * 4096 + threadIdx.x * 4;
    #pragma unroll
    for (int it = 0; it < 4; ++it) {
        const size_t k = base + it * 1024;
        const f32x4 p0 = *(const f32x4*)&s0[k];
        const f32x4 p1 = *(const f32x4*)&s1[k];
        const f32x4 xv = *(const f32x4*)&x[k];
        f32x4 o, y;
        #pragma unroll
        for (int r = 0; r < 4; ++r) {
            o[r] = fmaxf(p0[r] + p1[r], 0.0f);
            y[r] = fmaf(gamma, o[r], xv[r]);
        }
        *(f32x4*)&s0[k] = y;
        *(f32x4*)&s1[k] = o;
    }
}

extern "C" void kernel_launch(void* const* d_in, const int* in_sizes, int n_in,
                              void* d_out, int out_size, void* d_ws, size_t ws_size,
                              hipStream_t stream) {
    const float* x       = (const float*)d_in[0];
    const float* gamma_p = (const float*)d_in[1];
    float* out = (float*)d_out;

    // ws layout (~14.5 MB): row_d (8x3200 f32) | xt | xcp
    float* row_d = (float*)d_ws;
    u16* xt  = (u16*)((char*)d_ws + (1 << 17));
    u16* xcp = xt + (size_t)Bb * Np * PADX;

    (void)hipMemsetAsync(row_d, 0, (size_t)Bb * Np * sizeof(float), stream);
    prep_kernel  <<<400, 256, 0, stream>>>(x, gamma_p, out, xt, xcp, row_d);
    stats_kernel <<<784, 256, 0, stream>>>(xt, row_d);
    out_kernel   <<<784, 256, 0, stream>>>(xt, xcp, row_d, out);
    reduce_kernel<<<784, 256, 0, stream>>>(x, gamma_p, out);
}